// Round 12
// baseline (351.668 us; speedup 1.0000x reference)
//
#include <hip/hip_runtime.h>

#define N_NODES 50000
#define N_EDGES 800000
#define D 64
#define CAP 64
#define XLD 72      // LDS row stride (bf16 elems) for the MFMA X tile
#define SENT 50000  // sentinel row index (-inf row), fits in ushort
#define NBINS 196   // ceil(50000/256) nodes per bin = 256
#define NREP 4      // bin-counter replicas (contention /4)
#define REPCAP 1536 // per-replica bin capacity (mean 1024, +16 sigma)

typedef short short8 __attribute__((ext_vector_type(8)));
typedef float floatx4 __attribute__((ext_vector_type(4)));
typedef unsigned short ushort_t;

__device__ __forceinline__ ushort_t f32_to_bf16(float f) {
    unsigned int u = __float_as_uint(f);
    u += 0x7FFFu + ((u >> 16) & 1u);   // RNE; finite inputs
    return (ushort_t)(u >> 16);
}
__device__ __forceinline__ float bf16lo(unsigned int u) { return __uint_as_float(u << 16); }
__device__ __forceinline__ float bf16hi(unsigned int u) { return __uint_as_float(u & 0xFFFF0000u); }

// 3125 blocks: n_feat f32 -> hb0 bf16. Blocks 0..2: W transpose; block 0: -inf
// sentinel rows; block 3: zero the replicated bin counters.
__global__ void __launch_bounds__(256) cvtw_kernel(const float* __restrict__ in,
                                                   ushort_t* __restrict__ hb0,
                                                   ushort_t* __restrict__ hb1,
                                                   const float* __restrict__ W0,
                                                   const float* __restrict__ W1,
                                                   const float* __restrict__ W2,
                                                   ushort_t* __restrict__ wt_all,
                                                   int* __restrict__ bin_cnt) {
    int b = blockIdx.x;
    int t = b * 256 + threadIdx.x;               // 800000 threads, 4 elems each
    float4 v = ((const float4*)in)[t];
    uint2 o;
    o.x = ((unsigned)f32_to_bf16(v.y) << 16) | f32_to_bf16(v.x);
    o.y = ((unsigned)f32_to_bf16(v.w) << 16) | f32_to_bf16(v.z);
    ((uint2*)hb0)[t] = o;
    if (b < 3) {
        const float* Ws[3] = {W0, W1, W2};
        const float* W = Ws[b];
        ushort_t* ow = wt_all + b * 4096;
        for (int idx = threadIdx.x; idx < 4096; idx += 256) {
            int k = idx >> 6, n = idx & 63;      // W row-major [k][n] -> wt [n][k]
            ow[n * 64 + k] = f32_to_bf16(W[idx]);
        }
        if (b == 0) {
            int l = threadIdx.x;
            if (l < 64) hb0[(size_t)SENT * 64 + l] = 0xFF80u;            // bf16 -inf
            else if (l < 128) hb1[(size_t)SENT * 64 + (l - 64)] = 0xFF80u;
        }
    } else if (b == 3) {
#pragma unroll
        for (int i = 0; i < NREP; ++i) bin_cnt[i * 256 + threadIdx.x] = 0;
    }
}

// Level 1: append (dst&255, src) to coarse bin dst>>8. Appends to 784 hot
// streams line-merge in L2 (vs 44MB line-granular scatter of the old fill).
__global__ void __launch_bounds__(256) binscatter_kernel(const int* __restrict__ src,
                                                         const int* __restrict__ dst,
                                                         int* __restrict__ bin_cnt,
                                                         unsigned int* __restrict__ binbuf) {
    int e = blockIdx.x * 256 + threadIdx.x;      // 800000 edges exact
    int s = src[e];
    int t = dst[e];
    int bin = t >> 8;
    int rep = threadIdx.x & (NREP - 1);
    int pos = atomicAdd(&bin_cnt[rep * 256 + bin], 1);
    if (pos < REPCAP)
        binbuf[(size_t)bin * (NREP * REPCAP) + rep * REPCAP + pos] =
            ((unsigned)(t & 255) << 16) | (unsigned)s;
}

// Level 2: one block per bin. LDS-staged bucket rows (SENT-prefilled), LDS
// atomic slot alloc, then fully coalesced 32KB dump + cnt dump.
__global__ void __launch_bounds__(256) binbuild_kernel(const int* __restrict__ bin_cnt,
                                                       const unsigned int* __restrict__ binbuf,
                                                       int* __restrict__ cnt,
                                                       ushort_t* __restrict__ bucket) {
    __shared__ int lcnt[256];
    __shared__ ushort_t lbkt[256 * CAP];         // 32 KB
    const int tid = threadIdx.x;
    const int bin = blockIdx.x;

    lcnt[tid] = 0;
    {   // prefill buckets with SENT (defense: un-written slots -> -inf row)
        const unsigned int sp = ((unsigned)SENT << 16) | (unsigned)SENT;
        uint4 s4 = {sp, sp, sp, sp};
        uint4* lb4 = (uint4*)lbkt;
#pragma unroll
        for (int i = 0; i < 8; ++i) lb4[tid + 256 * i] = s4;   // 2048 uint4
    }
    __syncthreads();

    const unsigned int* buf = binbuf + (size_t)bin * (NREP * REPCAP);
#pragma unroll 1
    for (int rep = 0; rep < NREP; ++rep) {
        int ne = min(bin_cnt[rep * 256 + bin], REPCAP);
        const unsigned int* b = buf + rep * REPCAP;
        for (int i = tid; i < ne; i += 256) {
            unsigned int u = b[i];
            int dlow = (u >> 16) & 255;
            int slot = atomicAdd(&lcnt[dlow], 1);
            if (slot < CAP) lbkt[dlow * CAP + slot] = (ushort_t)(u & 0xFFFFu);
        }
    }
    __syncthreads();

    const int nrows = min(256, N_NODES - bin * 256);       // 256, last bin: 80
    if (tid < nrows) cnt[bin * 256 + tid] = lcnt[tid];
    const int nchunk = nrows * 8;                          // 8 uint4 per row
    const uint4* lb4 = (const uint4*)lbkt;
    uint4* gb4 = (uint4*)(bucket + (size_t)bin * 256 * CAP);
    for (int i = tid; i < nchunk; i += 256) gb4[i] = lb4[i];
}

#define RED4(ua, ub, uc, ud)                                                                        \
    m0 = fmaxf(m0, fmaxf(fmaxf(bf16lo(ua.x), bf16lo(ub.x)), fmaxf(bf16lo(uc.x), bf16lo(ud.x))));    \
    m1 = fmaxf(m1, fmaxf(fmaxf(bf16hi(ua.x), bf16hi(ub.x)), fmaxf(bf16hi(uc.x), bf16hi(ud.x))));    \
    m2 = fmaxf(m2, fmaxf(fmaxf(bf16lo(ua.y), bf16lo(ub.y)), fmaxf(bf16lo(uc.y), bf16lo(ud.y))));    \
    m3 = fmaxf(m3, fmaxf(fmaxf(bf16hi(ua.y), bf16hi(ub.y)), fmaxf(bf16hi(uc.y), bf16hi(ud.y))));

// UNCHANGED from R11 (clean A/B on the build path; layer counters next round).
__global__ void __launch_bounds__(256) layer_kernel(
        const ushort_t* __restrict__ hin,
        const int* __restrict__ cnt,
        const ushort_t* __restrict__ bucket,
        const ushort_t* __restrict__ wt,   // this layer's W^T bf16 [n][k]
        const float* __restrict__ bias,
        const float* __restrict__ eps_arr,
        int layer, int activate, int last,
        ushort_t* __restrict__ out_bf,
        float* __restrict__ out_f32) {
    __shared__ ushort_t bk[16 * CAP];    // 2 KB: block's 16 bucket rows
    __shared__ ushort_t xs[16 * XLD];    // 2.3 KB: X tile for MFMA

    const int tid = threadIdx.x;
    const int lane = tid & 63;
    const int wv = tid >> 6;
    const int grp = lane >> 4;           // which of the wave's 4 rows this lane serves
    const int l15 = lane & 15;
    const int fo = l15 * 4;              // first of 4 feature elems for this lane
    const float ev = 1.0f + eps_arr[layer];

    const int r0 = blockIdx.x * 16 + wv * 4;

    // stage this wave's 4 bucket rows into LDS (wave-private)
#pragma unroll
    for (int j = 0; j < 4; ++j)
        bk[(wv * 4 + j) * CAP + lane] = bucket[(r0 + j) * CAP + lane];

    const int rr = r0 + grp;             // this lane's row
    const int cg = min(cnt[rr], CAP);
    // wave-uniform bound: roundup16 of the max count over the 4 groups
    int g0 = __builtin_amdgcn_readlane(cg, 0);
    int g1 = __builtin_amdgcn_readlane(cg, 16);
    int g2 = __builtin_amdgcn_readlane(cg, 32);
    int g3 = __builtin_amdgcn_readlane(cg, 48);
    const int cmax = (max(max(g0, g1), max(g2, g3)) + 15) & ~15;

    ushort_t* bkrow = &bk[(wv * 4 + grp) * CAP];
    // pad [cg, cmax) of every row with SENT (16 lanes, strided)
    for (int s = cg + l15; s < cmax; s += 16) bkrow[s] = (ushort_t)SENT;

    const uint2 sv = *(const uint2*)&hin[rr * 64 + fo];    // self row (4 feats)

    float m0 = -INFINITY, m1 = -INFINITY, m2 = -INFINITY, m3 = -INFINITY;
    for (int i = 0; i < cmax; i += 16) {
        ushort4 sa = *(const ushort4*)&bkrow[i];           // 4x ds_read_b64
        ushort4 sb = *(const ushort4*)&bkrow[i + 4];
        ushort4 sc = *(const ushort4*)&bkrow[i + 8];
        ushort4 sd = *(const ushort4*)&bkrow[i + 12];
        uint2 u0  = *(const uint2*)&hin[(int)sa.x * 64 + fo];   // 16 independent loads
        uint2 u1  = *(const uint2*)&hin[(int)sa.y * 64 + fo];
        uint2 u2  = *(const uint2*)&hin[(int)sa.z * 64 + fo];
        uint2 u3  = *(const uint2*)&hin[(int)sa.w * 64 + fo];
        uint2 u4  = *(const uint2*)&hin[(int)sb.x * 64 + fo];
        uint2 u5  = *(const uint2*)&hin[(int)sb.y * 64 + fo];
        uint2 u6  = *(const uint2*)&hin[(int)sb.z * 64 + fo];
        uint2 u7  = *(const uint2*)&hin[(int)sb.w * 64 + fo];
        uint2 u8  = *(const uint2*)&hin[(int)sc.x * 64 + fo];
        uint2 u9  = *(const uint2*)&hin[(int)sc.y * 64 + fo];
        uint2 u10 = *(const uint2*)&hin[(int)sc.z * 64 + fo];
        uint2 u11 = *(const uint2*)&hin[(int)sc.w * 64 + fo];
        uint2 u12 = *(const uint2*)&hin[(int)sd.x * 64 + fo];
        uint2 u13 = *(const uint2*)&hin[(int)sd.y * 64 + fo];
        uint2 u14 = *(const uint2*)&hin[(int)sd.z * 64 + fo];
        uint2 u15 = *(const uint2*)&hin[(int)sd.w * 64 + fo];
        RED4(u0, u1, u2, u3)
        RED4(u4, u5, u6, u7)
        RED4(u8, u9, u10, u11)
        RED4(u12, u13, u14, u15)
    }
    float a0 = (cg > 0) ? m0 : 0.f, a1 = (cg > 0) ? m1 : 0.f;   // DGL: no in-edges -> 0
    float a2 = (cg > 0) ? m2 : 0.f, a3 = (cg > 0) ? m3 : 0.f;
    float x0 = fmaf(ev, bf16lo(sv.x), a0), x1 = fmaf(ev, bf16hi(sv.x), a1);
    float x2 = fmaf(ev, bf16lo(sv.y), a2), x3 = fmaf(ev, bf16hi(sv.y), a3);
    uint2 w;
    w.x = ((unsigned)f32_to_bf16(x1) << 16) | f32_to_bf16(x0);
    w.y = ((unsigned)f32_to_bf16(x3) << 16) | f32_to_bf16(x2);
    *(uint2*)&xs[(wv * 4 + grp) * XLD + fo] = w;
    __syncthreads();                      // xs rows 0..15 read by all waves below

    // MFMA: one 16x16 N-tile per wave (nt = wv), K = 64 in 2 steps (layout verified)
    const int hi = lane >> 4;
    const int kc = hi * 8;
    short8 fa0 = *(const short8*)&xs[l15 * XLD + kc];
    short8 fa1 = *(const short8*)&xs[l15 * XLD + 32 + kc];
    const int ncol = wv * 16 + l15;
    short8 fb0 = *(const short8*)&wt[ncol * 64 + kc];      // L2-resident broadcast
    short8 fb1 = *(const short8*)&wt[ncol * 64 + 32 + kc];
    floatx4 acc = {0.f, 0.f, 0.f, 0.f};
    acc = __builtin_amdgcn_mfma_f32_16x16x32_bf16(fa0, fb0, acc, 0, 0, 0);
    acc = __builtin_amdgcn_mfma_f32_16x16x32_bf16(fa1, fb1, acc, 0, 0, 0);

    const float bv = bias[ncol];
#pragma unroll
    for (int i = 0; i < 4; ++i) {
        int grow = blockIdx.x * 16 + hi * 4 + i;          // D: col=lane&15, row=hi*4+i
        float v = acc[i] + bv;
        if (activate) v = (v >= 0.f) ? v : 0.01f * v;
        if (last) out_f32[(size_t)grow * 64 + ncol] = v;
        else out_bf[(size_t)grow * 64 + ncol] = f32_to_bf16(v);
    }
}

extern "C" void kernel_launch(void* const* d_in, const int* in_sizes, int n_in,
                              void* d_out, int out_size, void* d_ws, size_t ws_size,
                              hipStream_t stream) {
    const float* n_feat = (const float*)d_in[0];
    const float* W0 = (const float*)d_in[1];
    const float* b0 = (const float*)d_in[2];
    const float* W1 = (const float*)d_in[3];
    const float* b1 = (const float*)d_in[4];
    const float* W2 = (const float*)d_in[5];
    const float* b2 = (const float*)d_in[6];
    const float* eps = (const float*)d_in[7];
    const int* src = (const int*)d_in[8];
    const int* dst = (const int*)d_in[9];
    float* out = (float*)d_out;

    const size_t BINCNT_OFF = 0;                                   // 4*256*4 = 4096 B
    const size_t CNT_OFF    = 4096;                                // 200000 B
    const size_t BKT_OFF    = 204288;                              // 6,400,000 B
    const size_t BINBUF_OFF = 6604288;                             // 196*6144*4 = 4,816,896 B
    const size_t HB0_OFF    = 11421184;                            // 6,400,128 B
    const size_t HB1_OFF    = 17821312;                            // 6,400,128 B
    const size_t WT_OFF     = 24221440;                            // 24,576 B (~24.25 MB total)

    int* bin_cnt = (int*)((char*)d_ws + BINCNT_OFF);
    int* cnt = (int*)((char*)d_ws + CNT_OFF);
    ushort_t* bucket = (ushort_t*)((char*)d_ws + BKT_OFF);
    unsigned int* binbuf = (unsigned int*)((char*)d_ws + BINBUF_OFF);
    ushort_t* hb0 = (ushort_t*)((char*)d_ws + HB0_OFF);
    ushort_t* hb1 = (ushort_t*)((char*)d_ws + HB1_OFF);
    ushort_t* wt_all = (ushort_t*)((char*)d_ws + WT_OFF);

    cvtw_kernel<<<3125, 256, 0, stream>>>(n_feat, hb0, hb1, W0, W1, W2, wt_all, bin_cnt);
    binscatter_kernel<<<3125, 256, 0, stream>>>(src, dst, bin_cnt, binbuf);
    binbuild_kernel<<<NBINS, 256, 0, stream>>>(bin_cnt, binbuf, cnt, bucket);

    dim3 blk(256);
    // L0: hb0 -> hb1, L1: hb1 -> hb0, L2: hb0 -> out (f32)
    layer_kernel<<<3125, blk, 0, stream>>>(hb0, cnt, bucket, wt_all,        b0, eps, 0, 1, 0, hb1, out);
    layer_kernel<<<3125, blk, 0, stream>>>(hb1, cnt, bucket, wt_all + 4096, b1, eps, 1, 1, 0, hb0, out);
    layer_kernel<<<3125, blk, 0, stream>>>(hb0, cnt, bucket, wt_all + 8192, b2, eps, 2, 0, 1, hb1, out);
}

// Round 13
// 180.916 us; speedup vs baseline: 1.9438x; 1.9438x over previous
//
#include <hip/hip_runtime.h>

#define N_NODES 50000
#define N_EDGES 800000
#define D 64
#define CAP 64
#define XLD 72      // LDS row stride (bf16 elems) for the MFMA X tile
#define SENT 50000  // sentinel row index (-inf row), fits in ushort

typedef short short8 __attribute__((ext_vector_type(8)));
typedef float floatx4 __attribute__((ext_vector_type(4)));
typedef unsigned short ushort_t;

__device__ __forceinline__ ushort_t f32_to_bf16(float f) {
    unsigned int u = __float_as_uint(f);
    u += 0x7FFFu + ((u >> 16) & 1u);   // RNE; finite inputs
    return (ushort_t)(u >> 16);
}
__device__ __forceinline__ float bf16lo(unsigned int u) { return __uint_as_float(u << 16); }
__device__ __forceinline__ float bf16hi(unsigned int u) { return __uint_as_float(u & 0xFFFF0000u); }

// 3125 blocks: n_feat f32 -> hb0 bf16. Blocks 0..2: W transpose; block 0: -inf
// sentinel rows; blocks 4..199: zero cnt (no separate memset dispatch).
__global__ void __launch_bounds__(256) cvtw_kernel(const float* __restrict__ in,
                                                   ushort_t* __restrict__ hb0,
                                                   ushort_t* __restrict__ hb1,
                                                   const float* __restrict__ W0,
                                                   const float* __restrict__ W1,
                                                   const float* __restrict__ W2,
                                                   ushort_t* __restrict__ wt_all,
                                                   int* __restrict__ cnt) {
    int b = blockIdx.x;
    int t = b * 256 + threadIdx.x;               // 800000 threads, 4 elems each
    float4 v = ((const float4*)in)[t];
    uint2 o;
    o.x = ((unsigned)f32_to_bf16(v.y) << 16) | f32_to_bf16(v.x);
    o.y = ((unsigned)f32_to_bf16(v.w) << 16) | f32_to_bf16(v.z);
    ((uint2*)hb0)[t] = o;
    if (b < 3) {
        const float* Ws[3] = {W0, W1, W2};
        const float* W = Ws[b];
        ushort_t* ow = wt_all + b * 4096;
        for (int idx = threadIdx.x; idx < 4096; idx += 256) {
            int k = idx >> 6, n = idx & 63;      // W row-major [k][n] -> wt [n][k]
            ow[n * 64 + k] = f32_to_bf16(W[idx]);
        }
        if (b == 0) {
            int l = threadIdx.x;
            if (l < 64) hb0[(size_t)SENT * 64 + l] = 0xFF80u;            // bf16 -inf
            else if (l < 128) hb1[(size_t)SENT * 64 + (l - 64)] = 0xFF80u;
        }
    } else if (b >= 4 && b < 200) {
        int i = (b - 4) * 256 + threadIdx.x;
        if (i < N_NODES) cnt[i] = 0;
    }
}

// XCD-partitioned bucket fill: block handles dst-range r = blockIdx&7
// (round-robin block->XCD => each bucket line dirtied by ONE XCD's L2 only;
// if the mapping heuristic is wrong, correctness is unaffected).
// Every block streams a 2048-edge chunk (int4-coalesced) and filters.
__global__ void __launch_bounds__(256) fillx_kernel(const int* __restrict__ src,
                                                    const int* __restrict__ dst,
                                                    int* __restrict__ cnt,
                                                    ushort_t* __restrict__ bucket) {
    const int r = blockIdx.x & 7;                // dst-range id (dst/6250)
    const int base4 = (blockIdx.x >> 3) * 512;   // int4 index base, chunks of 2048 edges
    const int4* d4 = (const int4*)dst;
    const int4* s4 = (const int4*)src;
#pragma unroll 1
    for (int i = threadIdx.x; i < 512; i += 256) {
        int idx = base4 + i;
        if (idx < N_EDGES / 4) {
            int4 d = d4[idx];
            int4 s = s4[idx];
            if (d.x / 6250 == r) { int sl = atomicAdd(&cnt[d.x], 1); if (sl < CAP) bucket[d.x * CAP + sl] = (ushort_t)s.x; }
            if (d.y / 6250 == r) { int sl = atomicAdd(&cnt[d.y], 1); if (sl < CAP) bucket[d.y * CAP + sl] = (ushort_t)s.y; }
            if (d.z / 6250 == r) { int sl = atomicAdd(&cnt[d.z], 1); if (sl < CAP) bucket[d.z * CAP + sl] = (ushort_t)s.z; }
            if (d.w / 6250 == r) { int sl = atomicAdd(&cnt[d.w], 1); if (sl < CAP) bucket[d.w * CAP + sl] = (ushort_t)s.w; }
        }
    }
}

#define RED4(ua, ub, uc, ud)                                                                        \
    m0 = fmaxf(m0, fmaxf(fmaxf(bf16lo(ua.x), bf16lo(ub.x)), fmaxf(bf16lo(uc.x), bf16lo(ud.x))));    \
    m1 = fmaxf(m1, fmaxf(fmaxf(bf16hi(ua.x), bf16hi(ub.x)), fmaxf(bf16hi(uc.x), bf16hi(ud.x))));    \
    m2 = fmaxf(m2, fmaxf(fmaxf(bf16lo(ua.y), bf16lo(ub.y)), fmaxf(bf16lo(uc.y), bf16lo(ud.y))));    \
    m3 = fmaxf(m3, fmaxf(fmaxf(bf16hi(ua.y), bf16hi(ub.y)), fmaxf(bf16hi(uc.y), bf16hi(ud.y))));

// layer_kernel: R9-verbatim (measured-best ~40us/layer; line-request bound).
__global__ void __launch_bounds__(256) layer_kernel(
        const ushort_t* __restrict__ hin,
        const int* __restrict__ cnt,
        const ushort_t* __restrict__ bucket,
        const ushort_t* __restrict__ wt,   // this layer's W^T bf16 [n][k]
        const float* __restrict__ bias,
        const float* __restrict__ eps_arr,
        int layer, int activate, int last,
        ushort_t* __restrict__ out_bf,
        float* __restrict__ out_f32) {
    __shared__ ushort_t bk[16 * CAP];    // 2 KB: block's 16 bucket rows
    __shared__ ushort_t xs[16 * XLD];    // 2.3 KB: X tile for MFMA

    const int tid = threadIdx.x;
    const int lane = tid & 63;
    const int wv = tid >> 6;
    const int grp = lane >> 4;           // which of the wave's 4 rows this lane serves
    const int l15 = lane & 15;
    const int fo = l15 * 4;              // first of 4 feature elems for this lane
    const float ev = 1.0f + eps_arr[layer];

    const int r0 = blockIdx.x * 16 + wv * 4;

    // stage this wave's 4 bucket rows into LDS (wave-private)
#pragma unroll
    for (int j = 0; j < 4; ++j)
        bk[(wv * 4 + j) * CAP + lane] = bucket[(r0 + j) * CAP + lane];

    const int rr = r0 + grp;             // this lane's row
    const int cg = min(cnt[rr], CAP);
    const int c4g = (cg + 3) & ~3;
    // pad [cg, c4g) with sentinel in the LDS copy (lanes l15<3 cover <=3 slots)
    {
        int s = cg + l15;
        if (s < c4g) bk[(wv * 4 + grp) * CAP + s] = (ushort_t)SENT;
    }
    // wave-uniform loop bound = max padded count over the 4 groups
    int c0 = __builtin_amdgcn_readlane(c4g, 0);
    int c1 = __builtin_amdgcn_readlane(c4g, 16);
    int c2 = __builtin_amdgcn_readlane(c4g, 32);
    int c3 = __builtin_amdgcn_readlane(c4g, 48);
    const int cmax = max(max(c0, c1), max(c2, c3));

    const uint2 sv = *(const uint2*)&hin[rr * 64 + fo];    // self row (4 feats)

    float m0 = -INFINITY, m1 = -INFINITY, m2 = -INFINITY, m3 = -INFINITY;
    const ushort_t* bkrow = &bk[(wv * 4 + grp) * CAP];
    for (int i = 0; i < cmax; i += 8) {
        if (i < c4g) {                   // chunk A (predicated per 16-lane group)
            ushort4 s4 = *(const ushort4*)&bkrow[i];       // one ds_read_b64
            uint2 u0 = *(const uint2*)&hin[(int)s4.x * 64 + fo];
            uint2 u1 = *(const uint2*)&hin[(int)s4.y * 64 + fo];
            uint2 u2 = *(const uint2*)&hin[(int)s4.z * 64 + fo];
            uint2 u3 = *(const uint2*)&hin[(int)s4.w * 64 + fo];
            RED4(u0, u1, u2, u3)
        }
        if (i + 4 < c4g) {               // chunk B: up to 8 loads in flight
            ushort4 s4 = *(const ushort4*)&bkrow[i + 4];
            uint2 u0 = *(const uint2*)&hin[(int)s4.x * 64 + fo];
            uint2 u1 = *(const uint2*)&hin[(int)s4.y * 64 + fo];
            uint2 u2 = *(const uint2*)&hin[(int)s4.z * 64 + fo];
            uint2 u3 = *(const uint2*)&hin[(int)s4.w * 64 + fo];
            RED4(u0, u1, u2, u3)
        }
    }
    float a0 = (cg > 0) ? m0 : 0.f, a1 = (cg > 0) ? m1 : 0.f;   // DGL: no in-edges -> 0
    float a2 = (cg > 0) ? m2 : 0.f, a3 = (cg > 0) ? m3 : 0.f;
    float x0 = fmaf(ev, bf16lo(sv.x), a0), x1 = fmaf(ev, bf16hi(sv.x), a1);
    float x2 = fmaf(ev, bf16lo(sv.y), a2), x3 = fmaf(ev, bf16hi(sv.y), a3);
    uint2 w;
    w.x = ((unsigned)f32_to_bf16(x1) << 16) | f32_to_bf16(x0);
    w.y = ((unsigned)f32_to_bf16(x3) << 16) | f32_to_bf16(x2);
    *(uint2*)&xs[(wv * 4 + grp) * XLD + fo] = w;
    __syncthreads();                      // xs rows 0..15 read by all waves below

    // MFMA: one 16x16 N-tile per wave (nt = wv), K = 64 in 2 steps (layout verified)
    const int hi = lane >> 4;
    const int kc = hi * 8;
    short8 fa0 = *(const short8*)&xs[l15 * XLD + kc];
    short8 fa1 = *(const short8*)&xs[l15 * XLD + 32 + kc];
    const int ncol = wv * 16 + l15;
    short8 fb0 = *(const short8*)&wt[ncol * 64 + kc];      // L2-resident broadcast
    short8 fb1 = *(const short8*)&wt[ncol * 64 + 32 + kc];
    floatx4 acc = {0.f, 0.f, 0.f, 0.f};
    acc = __builtin_amdgcn_mfma_f32_16x16x32_bf16(fa0, fb0, acc, 0, 0, 0);
    acc = __builtin_amdgcn_mfma_f32_16x16x32_bf16(fa1, fb1, acc, 0, 0, 0);

    const float bv = bias[ncol];
#pragma unroll
    for (int i = 0; i < 4; ++i) {
        int grow = blockIdx.x * 16 + hi * 4 + i;          // D: col=lane&15, row=hi*4+i
        float v = acc[i] + bv;
        if (activate) v = (v >= 0.f) ? v : 0.01f * v;
        if (last) out_f32[(size_t)grow * 64 + ncol] = v;
        else out_bf[(size_t)grow * 64 + ncol] = f32_to_bf16(v);
    }
}

extern "C" void kernel_launch(void* const* d_in, const int* in_sizes, int n_in,
                              void* d_out, int out_size, void* d_ws, size_t ws_size,
                              hipStream_t stream) {
    const float* n_feat = (const float*)d_in[0];
    const float* W0 = (const float*)d_in[1];
    const float* b0 = (const float*)d_in[2];
    const float* W1 = (const float*)d_in[3];
    const float* b1 = (const float*)d_in[4];
    const float* W2 = (const float*)d_in[5];
    const float* b2 = (const float*)d_in[6];
    const float* eps = (const float*)d_in[7];
    const int* src = (const int*)d_in[8];
    const int* dst = (const int*)d_in[9];
    float* out = (float*)d_out;

    const size_t BKT_OFF = 200192;                                 // cnt 200000B, padded
    const size_t HB0_OFF = BKT_OFF + (size_t)N_NODES * CAP * 2;    // bucket 6.4 MB
    const size_t HB1_OFF = HB0_OFF + (size_t)(N_NODES + 1) * 64 * 2;
    const size_t WT_OFF  = HB1_OFF + (size_t)(N_NODES + 1) * 64 * 2;

    int* cnt = (int*)d_ws;
    ushort_t* bucket = (ushort_t*)((char*)d_ws + BKT_OFF);
    ushort_t* hb0 = (ushort_t*)((char*)d_ws + HB0_OFF);
    ushort_t* hb1 = (ushort_t*)((char*)d_ws + HB1_OFF);
    ushort_t* wt_all = (ushort_t*)((char*)d_ws + WT_OFF);          // 24,576 B

    cvtw_kernel<<<3125, 256, 0, stream>>>(n_feat, hb0, hb1, W0, W1, W2, wt_all, cnt);
    fillx_kernel<<<8 * 391, 256, 0, stream>>>(src, dst, cnt, bucket);   // 3128 blocks

    dim3 blk(256);
    // L0: hb0 -> hb1, L1: hb1 -> hb0, L2: hb0 -> out (f32)
    layer_kernel<<<3125, blk, 0, stream>>>(hb0, cnt, bucket, wt_all,        b0, eps, 0, 1, 0, hb1, out);
    layer_kernel<<<3125, blk, 0, stream>>>(hb1, cnt, bucket, wt_all + 4096, b1, eps, 1, 1, 0, hb0, out);
    layer_kernel<<<3125, blk, 0, stream>>>(hb0, cnt, bucket, wt_all + 8192, b2, eps, 2, 0, 1, hb1, out);
}